// Round 1
// baseline (649.114 us; speedup 1.0000x reference)
//
#include <hip/hip_runtime.h>
#include <stdint.h>

// RPNHead fused: 3x3 conv(256->512,SAME)+relu6 -> {1x1 conv->30 + softmax-pairs, 1x1 conv->60}
// B=8 H=128 W=128. One block per (b,h) image row: M=128 pos, N=512 ch, K=2304.
// bf16 MFMA 16x16x32. 8 waves: 2(M)x4(N), per-wave 64x128 acc.
// LDS: A row [130][256] bf16 XOR-swizzled (66560 B) + B chunk [512][64] bf16 n-major,
// pre-swizzled in global so staging is linear global_load_lds (132096 B total, 1 block/CU).

#define HH 128
#define WW 128
#define CIN 256

typedef __attribute__((ext_vector_type(8))) short short8;
typedef __attribute__((ext_vector_type(4))) float f32x4;

#define LDS_B_OFF 66560
#define LDS_TOTAL 132096

static __device__ __forceinline__ unsigned short f2bf(float f) {
    uint32_t u = __float_as_uint(f);
    uint32_t r = (u + 0x7FFFu + ((u >> 16) & 1u)) >> 16;
    return (unsigned short)r;
}

// w_shared [3][3][256][512] f32 -> wk [9*4 chunks][512 n][64 kk] bf16, n-major,
// kk position pre-swizzled: in-row byte = (kk*2) ^ ((n&7)<<4)  (so LDS copy is linear)
__global__ __launch_bounds__(256) void prep_wk(const float* __restrict__ w,
                                               unsigned short* __restrict__ wk) {
    int t = blockIdx.x * 256 + threadIdx.x;          // 1,179,648 total
    int c_idx = t >> 15;                              // dydx*4 + kc
    int r = t & 32767;
    int n = r >> 6, kk = r & 63;
    int dydx = c_idx >> 2, kc = c_idx & 3;
    int k = kc * 64 + kk;
    float v = w[((size_t)(dydx * 256 + k)) * 512 + n];
    int sw = (((kk * 2) ^ ((n & 7) << 4)) >> 1);
    wk[(size_t)c_idx * 32768 + n * 64 + sw] = f2bf(v);
}

// w_cls [512][30], w_reg [512][60] -> wbr [96 n][512 k] bf16 (n-major; n 0..29=cls, 32..91=reg, rest 0)
__global__ __launch_bounds__(256) void prep_wbr(const float* __restrict__ wc,
                                                const float* __restrict__ wr,
                                                unsigned short* __restrict__ wbr) {
    int t = blockIdx.x * 256 + threadIdx.x;          // 49,152 total
    int n = t >> 9, k = t & 511;
    float v = 0.f;
    if (n < 30) v = wc[k * 30 + n];
    else if (n >= 32 && n < 92) v = wr[k * 60 + (n - 32)];
    wbr[n * 512 + k] = f2bf(v);
}

__global__ __launch_bounds__(512) void rpn_fused(
    const float* __restrict__ x, const unsigned short* __restrict__ wk,
    const float* __restrict__ bsh, const unsigned short* __restrict__ wbr,
    const float* __restrict__ bcls, const float* __restrict__ breg,
    float* __restrict__ out)
{
    extern __shared__ char smem[];
    const int tid = threadIdx.x;
    const int lane = tid & 63;
    const int wid = tid >> 6;            // 0..7
    const int wm = wid >> 2, wn = wid & 3;
    const int l15 = lane & 15, l4 = lane >> 4;
    const int blk = blockIdx.x;
    const int bb = blk >> 7, h = blk & 127;

    f32x4 acc[4][8];
    #pragma unroll
    for (int i = 0; i < 4; ++i)
        #pragma unroll
        for (int j = 0; j < 8; ++j) acc[i][j] = (f32x4){0.f, 0.f, 0.f, 0.f};

    for (int dy = 0; dy < 3; ++dy) {
        __syncthreads();   // prior MFMA reads of A (and B) done before restaging A
        {
            const int hp = h + dy - 1;
            const bool hin = (hp >= 0) && (hp < HH);
            const float* xrow = x + ((size_t)(bb * HH + hp)) * WW * CIN;
            for (int u = tid; u < 130 * 32; u += 512) {
                const int pos = u >> 5, c8 = u & 31;
                const int wc = pos - 1;
                float4 f0 = make_float4(0.f,0.f,0.f,0.f), f1 = make_float4(0.f,0.f,0.f,0.f);
                if (hin && (unsigned)wc < WW) {
                    const float4* p = reinterpret_cast<const float4*>(xrow + (size_t)wc * CIN + c8 * 8);
                    f0 = p[0]; f1 = p[1];
                }
                short8 v;
                v[0]=(short)f2bf(f0.x); v[1]=(short)f2bf(f0.y);
                v[2]=(short)f2bf(f0.z); v[3]=(short)f2bf(f0.w);
                v[4]=(short)f2bf(f1.x); v[5]=(short)f2bf(f1.y);
                v[6]=(short)f2bf(f1.z); v[7]=(short)f2bf(f1.w);
                *reinterpret_cast<short8*>(smem + pos * 512 + ((c8 * 16) ^ ((pos & 7) << 4))) = v;
            }
        }
        for (int dx = 0; dx < 3; ++dx) {
            const int dydx = dy * 3 + dx;
            for (int kc = 0; kc < 4; ++kc) {
                if (!(dx == 0 && kc == 0)) __syncthreads();  // prev MFMA done before B overwrite
                {
                    const char* src = reinterpret_cast<const char*>(wk)
                                    + ((size_t)(dydx * 4 + kc)) * 65536 + tid * 16;
                    char* dst = smem + LDS_B_OFF + tid * 16;
                    #pragma unroll
                    for (int i = 0; i < 8; ++i) {
                        __builtin_amdgcn_global_load_lds(
                            reinterpret_cast<const uint32_t*>(src + i * 8192),
                            reinterpret_cast<uint32_t*>(dst + i * 8192), 16, 0, 0);
                    }
                }
                __syncthreads();  // staged B (and A at dy start) visible
                #pragma unroll
                for (int ks = 0; ks < 2; ++ks) {
                    short8 af[4];
                    const int ch = kc * 64 + ks * 32 + l4 * 8;    // cin within 256
                    #pragma unroll
                    for (int mf = 0; mf < 4; ++mf) {
                        const int row = wm * 64 + mf * 16 + l15 + dx;
                        af[mf] = *reinterpret_cast<const short8*>(
                            smem + row * 512 + ((ch * 2) ^ ((row & 7) << 4)));
                    }
                    const int kk = ks * 32 + l4 * 8;              // within 64-chunk
                    #pragma unroll
                    for (int nf = 0; nf < 8; ++nf) {
                        const int n = wn * 128 + nf * 16 + l15;
                        short8 bf = *reinterpret_cast<const short8*>(
                            smem + LDS_B_OFF + n * 128 + ((kk * 2) ^ ((n & 7) << 4)));
                        #pragma unroll
                        for (int mf = 0; mf < 4; ++mf)
                            acc[mf][nf] = __builtin_amdgcn_mfma_f32_16x16x32_bf16(
                                af[mf], bf, acc[mf][nf], 0, 0, 0);
                    }
                }
            }
        }
    }

    // ---- epilogue: bias + relu6 -> shared_act in LDS [128 pos][512 ch] bf16, swizzled
    __syncthreads();
    #pragma unroll
    for (int nf = 0; nf < 8; ++nf) {
        const int ch = wn * 128 + nf * 16 + l15;
        const float bv = bsh[ch];
        #pragma unroll
        for (int mf = 0; mf < 4; ++mf) {
            #pragma unroll
            for (int r = 0; r < 4; ++r) {
                const int pos = wm * 64 + mf * 16 + l4 * 4 + r;
                float v = acc[mf][nf][r] + bv;
                v = fminf(fmaxf(v, 0.f), 6.f);
                *reinterpret_cast<unsigned short*>(
                    smem + pos * 1024 + ((ch * 2) ^ ((pos & 7) << 4))) = f2bf(v);
            }
        }
    }
    __syncthreads();

    // ---- branch GEMM: per wave 16 pos x 96 out, K=512. A=shared_act(LDS), B=wbr(global, L2-hot)
    f32x4 bacc[6];
    #pragma unroll
    for (int nf = 0; nf < 6; ++nf) bacc[nf] = (f32x4){0.f,0.f,0.f,0.f};
    const int pos0 = wid * 16;
    #pragma unroll 4
    for (int kstep = 0; kstep < 16; ++kstep) {
        const int ch = kstep * 32 + l4 * 8;
        const int posr = pos0 + l15;
        short8 af = *reinterpret_cast<const short8*>(
            smem + posr * 1024 + ((ch * 2) ^ ((posr & 7) << 4)));
        #pragma unroll
        for (int nf = 0; nf < 6; ++nf) {
            const int n = nf * 16 + l15;
            short8 bfr = *reinterpret_cast<const short8*>(wbr + n * 512 + ch);
            bacc[nf] = __builtin_amdgcn_mfma_f32_16x16x32_bf16(af, bfr, bacc[nf], 0, 0, 0);
        }
    }

    // ---- branch epilogue: bias, pair-softmax (adjacent n -> shfl_xor 1), scattered f32 stores
    const size_t rowbase = (size_t)h * 128;
    #pragma unroll
    for (int nf = 0; nf < 2; ++nf) {                 // cls: n 0..31 (valid <30)
        const int n = nf * 16 + l15;
        const float bias = (n < 30) ? bcls[n] : 0.f;
        #pragma unroll
        for (int r = 0; r < 4; ++r) {
            float v = bacc[nf][r] + bias;
            float vo = __shfl_xor(v, 1);
            float mx = fmaxf(v, vo);
            float e  = __expf(v - mx), eo = __expf(vo - mx);
            float p  = e / (e + eo);
            if (n < 30) {
                const int wc = pos0 + l4 * 4 + r;
                const size_t anchor = (rowbase + wc) * 15 + (n >> 1);
                const size_t idx = (size_t)bb * 491520 + anchor * 2 + (n & 1);
                out[idx] = v;                        // rpn_class_logits
                out[3932160 + idx] = p;              // rpn_probs
            }
        }
    }
    #pragma unroll
    for (int nf = 2; nf < 6; ++nf) {                 // reg: n 32..95 (valid nr<60)
        const int n = nf * 16 + l15;
        const int nr = n - 32;
        const float bias = (nr < 60) ? breg[nr] : 0.f;
        #pragma unroll
        for (int r = 0; r < 4; ++r) {
            float v = bacc[nf][r] + bias;
            if (nr < 60) {
                const int wc = pos0 + l4 * 4 + r;
                const size_t anchor = (rowbase + wc) * 15 + (nr >> 2);
                out[7864320 + (size_t)bb * 983040 + anchor * 4 + (nr & 3)] = v;  // rpn_deltas
            }
        }
    }
}

extern "C" void kernel_launch(void* const* d_in, const int* in_sizes, int n_in,
                              void* d_out, int out_size, void* d_ws, size_t ws_size,
                              hipStream_t stream) {
    const float* x    = (const float*)d_in[0];
    const float* wsh  = (const float*)d_in[1];
    const float* bsh  = (const float*)d_in[2];
    const float* wcls = (const float*)d_in[3];
    const float* bcls = (const float*)d_in[4];
    const float* wreg = (const float*)d_in[5];
    const float* breg = (const float*)d_in[6];
    float* out = (float*)d_out;

    unsigned short* wk  = (unsigned short*)d_ws;          // 1,179,648 bf16 = 2.25 MiB
    unsigned short* wbr = wk + 1179648;                   // 49,152 bf16

    prep_wk <<<4608, 256, 0, stream>>>(wsh, wk);
    prep_wbr<<<192, 256, 0, stream>>>(wcls, wreg, wbr);

    hipFuncSetAttribute((const void*)rpn_fused,
                        hipFuncAttributeMaxDynamicSharedMemorySize, LDS_TOTAL);
    rpn_fused<<<1024, 512, LDS_TOTAL, stream>>>(x, wk, bsh, wbr, bcls, breg, out);
}

// Round 2
// 616.002 us; speedup vs baseline: 1.0538x; 1.0538x over previous
//
#include <hip/hip_runtime.h>
#include <stdint.h>

// RPNHead fused: 3x3 conv(256->512,SAME)+relu6 -> {1x1 conv->30 + softmax-pairs, 1x1 conv->60}
// B=8 H=128 W=128. One block per (b,h) row: M=128 pos, N=512 ch, K=2304.
// bf16 MFMA 16x16x32. 8 waves: 2(M)x4(N), per-wave 64x128 acc.
// R2: 2-deep pipelined B staging (72 chunks of [512 n][32 kk], double-buffered,
// counted vmcnt(4) so loads stay in flight across barriers), coalesced prep_wk.

#define HH 128
#define WW 128
#define CIN 256

typedef __attribute__((ext_vector_type(8))) short short8;
typedef __attribute__((ext_vector_type(4))) float f32x4;

#define LDS_B_OFF 66560            // A: [130 pos][256 ch] bf16 swizzled = 66560 B
#define LDS_TOTAL 132096           // + 2 x 32768 B chunk buffers

static __device__ __forceinline__ unsigned short f2bf(float f) {
    uint32_t u = __float_as_uint(f);
    uint32_t r = (u + 0x7FFFu + ((u >> 16) & 1u)) >> 16;
    return (unsigned short)r;
}

// w_shared [3][3][256][512] f32 -> wk [72 chunks][512 n][32 kk] bf16 (chunk c: dydx=c/8, kc=c%8)
// LDS-transpose so global reads AND writes are coalesced.
__global__ __launch_bounds__(256) void prep_wk(const float* __restrict__ w,
                                               unsigned short* __restrict__ wk) {
    __shared__ unsigned short t[32][130];
    const int c = blockIdx.x >> 2, nh = blockIdx.x & 3;
    const int dydx = c >> 3, kc = c & 7;
    #pragma unroll
    for (int e = 0; e < 16; ++e) {
        int idx = e * 256 + threadIdx.x;          // 32 kk x 128 n
        int kk = idx >> 7, n0 = idx & 127;
        float v = w[((size_t)(dydx * 256 + kc * 32 + kk)) * 512 + nh * 128 + n0];
        t[kk][n0] = f2bf(v);
    }
    __syncthreads();
    #pragma unroll
    for (int e = 0; e < 16; ++e) {
        int idx = e * 256 + threadIdx.x;          // 128 n x 32 kk
        int n0 = idx >> 5, kk = idx & 31;
        wk[(size_t)c * 16384 + (size_t)(nh * 128 + n0) * 32 + kk] = t[kk][n0];
    }
}

// w_cls [512][30], w_reg [512][60] -> wbr [96 n][512 k] bf16 (n 0..29=cls, 32..91=reg, rest 0)
__global__ __launch_bounds__(256) void prep_wbr(const float* __restrict__ wc,
                                                const float* __restrict__ wr,
                                                unsigned short* __restrict__ wbr) {
    int t = blockIdx.x * 256 + threadIdx.x;       // 49,152 total
    int n = t >> 9, k = t & 511;
    float v = 0.f;
    if (n < 30) v = wc[k * 30 + n];
    else if (n >= 32 && n < 92) v = wr[k * 60 + (n - 32)];
    wbr[n * 512 + k] = f2bf(v);
}

__global__ __launch_bounds__(512, 2) void rpn_fused(
    const float* __restrict__ x, const unsigned short* __restrict__ wk,
    const float* __restrict__ bsh, const unsigned short* __restrict__ wbr,
    const float* __restrict__ bcls, const float* __restrict__ breg,
    float* __restrict__ out)
{
    extern __shared__ char smem[];
    const int tid = threadIdx.x;
    const int lane = tid & 63;
    const int wid = tid >> 6;            // 0..7
    const int wm = wid >> 2, wn = wid & 3;
    const int l15 = lane & 15, l4 = lane >> 4;
    const int blk = blockIdx.x;
    const int bb = blk >> 7, h = blk & 127;

    f32x4 acc[4][8];
    #pragma unroll
    for (int i = 0; i < 4; ++i)
        #pragma unroll
        for (int j = 0; j < 8; ++j) acc[i][j] = (f32x4){0.f, 0.f, 0.f, 0.f};

    // ---- prologue: stage chunk 0 into buf 0
    {
        const char* src = reinterpret_cast<const char*>(wk) + tid * 16;
        char* dst = smem + LDS_B_OFF + tid * 16;
        #pragma unroll
        for (int r = 0; r < 4; ++r)
            __builtin_amdgcn_global_load_lds(
                reinterpret_cast<const uint32_t*>(src + r * 8192),
                reinterpret_cast<uint32_t*>(dst + r * 8192), 16, 0, 0);
    }

    int g = 0;
    for (int dy = 0; dy < 3; ++dy) {
        // ---- A stage: rows protected by prev chunk's post-read barrier (or empty at dy=0)
        {
            const int hp = h + dy - 1;
            const bool hin = (hp >= 0) && (hp < HH);
            const float* xrow = x + ((size_t)(bb * HH + hp)) * WW * CIN;
            for (int u = tid; u < 130 * 32; u += 512) {
                const int pos = u >> 5, c8 = u & 31;
                const int wc = pos - 1;
                float4 f0 = make_float4(0.f,0.f,0.f,0.f), f1 = make_float4(0.f,0.f,0.f,0.f);
                if (hin && (unsigned)wc < WW) {
                    const float4* p = reinterpret_cast<const float4*>(xrow + (size_t)wc * CIN + c8 * 8);
                    f0 = p[0]; f1 = p[1];
                }
                short8 v;
                v[0]=(short)f2bf(f0.x); v[1]=(short)f2bf(f0.y);
                v[2]=(short)f2bf(f0.z); v[3]=(short)f2bf(f0.w);
                v[4]=(short)f2bf(f1.x); v[5]=(short)f2bf(f1.y);
                v[6]=(short)f2bf(f1.z); v[7]=(short)f2bf(f1.w);
                *reinterpret_cast<short8*>(smem + pos * 512 + ((c8 * 16) ^ ((pos & 7) << 4))) = v;
            }
        }
        for (int i = 0; i < 24; ++i, ++g) {
            const int nxt = g + 1;
            if (nxt < 72) {
                const char* src = reinterpret_cast<const char*>(wk) + (size_t)nxt * 32768 + tid * 16;
                char* dst = smem + LDS_B_OFF + ((nxt & 1) << 15) + tid * 16;
                #pragma unroll
                for (int r = 0; r < 4; ++r)
                    __builtin_amdgcn_global_load_lds(
                        reinterpret_cast<const uint32_t*>(src + r * 8192),
                        reinterpret_cast<uint32_t*>(dst + r * 8192), 16, 0, 0);
                if (i == 0) asm volatile("s_waitcnt vmcnt(4) lgkmcnt(0)" ::: "memory");
                else        asm volatile("s_waitcnt vmcnt(4)" ::: "memory");
            } else {
                asm volatile("s_waitcnt vmcnt(0) lgkmcnt(0)" ::: "memory");
            }
            __builtin_amdgcn_s_barrier();      // chunk g staged + A visible
            asm volatile("" ::: "memory");

            const int dx = (g >> 3) % 3;
            const int kc = g & 7;
            const char* bbuf = smem + LDS_B_OFF + ((g & 1) << 15);

            short8 af[4];
            const int ch = kc * 32 + l4 * 8;                  // cin within 256
            #pragma unroll
            for (int mf = 0; mf < 4; ++mf) {
                const int row = wm * 64 + mf * 16 + l15 + dx;
                af[mf] = *reinterpret_cast<const short8*>(
                    smem + row * 512 + ((ch * 2) ^ ((row & 7) << 4)));
            }
            short8 bf[8];
            #pragma unroll
            for (int nf = 0; nf < 8; ++nf) {
                const int n = wn * 128 + nf * 16 + l15;
                bf[nf] = *reinterpret_cast<const short8*>(bbuf + n * 64 + l4 * 16);
            }
            asm volatile("s_waitcnt lgkmcnt(0)" ::: "memory");
            __builtin_amdgcn_s_setprio(1);
            #pragma unroll
            for (int nf = 0; nf < 8; ++nf)
                #pragma unroll
                for (int mf = 0; mf < 4; ++mf)
                    acc[mf][nf] = __builtin_amdgcn_mfma_f32_16x16x32_bf16(
                        af[mf], bf[nf], acc[mf][nf], 0, 0, 0);
            __builtin_amdgcn_s_setprio(0);
            __builtin_amdgcn_s_barrier();      // all waves done reading buf[g&1] (and A for this dy's last chunk)
            asm volatile("" ::: "memory");
        }
    }

    // ---- epilogue: bias + relu6 -> shared_act in LDS [128 pos][512 ch] bf16, swizzled
    __syncthreads();
    #pragma unroll
    for (int nf = 0; nf < 8; ++nf) {
        const int ch = wn * 128 + nf * 16 + l15;
        const float bv = bsh[ch];
        #pragma unroll
        for (int mf = 0; mf < 4; ++mf) {
            #pragma unroll
            for (int r = 0; r < 4; ++r) {
                const int pos = wm * 64 + mf * 16 + l4 * 4 + r;
                float v = acc[mf][nf][r] + bv;
                v = fminf(fmaxf(v, 0.f), 6.f);
                *reinterpret_cast<unsigned short*>(
                    smem + pos * 1024 + ((ch * 2) ^ ((pos & 7) << 4))) = f2bf(v);
            }
        }
    }
    __syncthreads();

    // ---- branch GEMM: per wave 16 pos x 96 out, K=512. A=shared_act(LDS), B=wbr(global, L2-hot)
    f32x4 bacc[6];
    #pragma unroll
    for (int nf = 0; nf < 6; ++nf) bacc[nf] = (f32x4){0.f,0.f,0.f,0.f};
    const int pos0 = wid * 16;
    #pragma unroll 4
    for (int kstep = 0; kstep < 16; ++kstep) {
        const int ch = kstep * 32 + l4 * 8;
        const int posr = pos0 + l15;
        short8 af = *reinterpret_cast<const short8*>(
            smem + posr * 1024 + ((ch * 2) ^ ((posr & 7) << 4)));
        #pragma unroll
        for (int nf = 0; nf < 6; ++nf) {
            const int n = nf * 16 + l15;
            short8 bfr = *reinterpret_cast<const short8*>(wbr + n * 512 + ch);
            bacc[nf] = __builtin_amdgcn_mfma_f32_16x16x32_bf16(af, bfr, bacc[nf], 0, 0, 0);
        }
    }

    // ---- branch epilogue: bias, pair-softmax (adjacent n -> shfl_xor 1), scattered f32 stores
    const size_t rowbase = (size_t)h * 128;
    #pragma unroll
    for (int nf = 0; nf < 2; ++nf) {                 // cls: n 0..31 (valid <30)
        const int n = nf * 16 + l15;
        const float bias = (n < 30) ? bcls[n] : 0.f;
        #pragma unroll
        for (int r = 0; r < 4; ++r) {
            float v = bacc[nf][r] + bias;
            float vo = __shfl_xor(v, 1);
            float mx = fmaxf(v, vo);
            float e  = __expf(v - mx), eo = __expf(vo - mx);
            float p  = e / (e + eo);
            if (n < 30) {
                const int wc = pos0 + l4 * 4 + r;
                const size_t anchor = (rowbase + wc) * 15 + (n >> 1);
                const size_t idx = (size_t)bb * 491520 + anchor * 2 + (n & 1);
                out[idx] = v;                        // rpn_class_logits
                out[3932160 + idx] = p;              // rpn_probs
            }
        }
    }
    #pragma unroll
    for (int nf = 2; nf < 6; ++nf) {                 // reg: n 32..95 (valid nr<60)
        const int n = nf * 16 + l15;
        const int nr = n - 32;
        const float bias = (nr < 60) ? breg[nr] : 0.f;
        #pragma unroll
        for (int r = 0; r < 4; ++r) {
            float v = bacc[nf][r] + bias;
            if (nr < 60) {
                const int wc = pos0 + l4 * 4 + r;
                const size_t anchor = (rowbase + wc) * 15 + (nr >> 2);
                out[7864320 + (size_t)bb * 983040 + anchor * 4 + (nr & 3)] = v;  // rpn_deltas
            }
        }
    }
}

extern "C" void kernel_launch(void* const* d_in, const int* in_sizes, int n_in,
                              void* d_out, int out_size, void* d_ws, size_t ws_size,
                              hipStream_t stream) {
    const float* x    = (const float*)d_in[0];
    const float* wsh  = (const float*)d_in[1];
    const float* bsh  = (const float*)d_in[2];
    const float* wcls = (const float*)d_in[3];
    const float* bcls = (const float*)d_in[4];
    const float* wreg = (const float*)d_in[5];
    const float* breg = (const float*)d_in[6];
    float* out = (float*)d_out;

    unsigned short* wk  = (unsigned short*)d_ws;          // 72*512*32 = 1,179,648 bf16 = 2.25 MiB
    unsigned short* wbr = wk + 1179648;                   // 49,152 bf16

    prep_wk <<<288, 256, 0, stream>>>(wsh, wk);
    prep_wbr<<<192, 256, 0, stream>>>(wcls, wreg, wbr);

    hipFuncSetAttribute((const void*)rpn_fused,
                        hipFuncAttributeMaxDynamicSharedMemorySize, LDS_TOTAL);
    rpn_fused<<<1024, 512, LDS_TOTAL, stream>>>(x, wk, bsh, wbr, bcls, breg, out);
}

// Round 3
// 602.523 us; speedup vs baseline: 1.0773x; 1.0224x over previous
//
#include <hip/hip_runtime.h>
#include <stdint.h>

// RPNHead fused: 3x3 conv(256->512,SAME)+relu6 -> {1x1 conv->30 + softmax-pairs, 1x1 conv->60}
// B=8 H=128 W=128. One block per (b,h) row: M=128 pos, N=512 ch, K=2304.
// bf16 MFMA 16x16x32. 8 waves: 2(M)x4(N), per-wave 64x128 acc.
// R3: B-chunk XOR-swizzle (kk ^ ((n>>1)&3)<<3, both-sides via prep pre-swizzle) kills the
// 8-way bank conflict; lgkmcnt(0) drain before MFMA removed -> compiler counted-lgkm interleave.

#define HH 128
#define WW 128
#define CIN 256

typedef __attribute__((ext_vector_type(8))) short short8;
typedef __attribute__((ext_vector_type(4))) float f32x4;

#define LDS_B_OFF 66560            // A: [130 pos][256 ch] bf16 swizzled = 66560 B
#define LDS_TOTAL 132096           // + 2 x 32768 B chunk buffers

static __device__ __forceinline__ unsigned short f2bf(float f) {
    uint32_t u = __float_as_uint(f);
    uint32_t r = (u + 0x7FFFu + ((u >> 16) & 1u)) >> 16;
    return (unsigned short)r;
}

// w_shared [3][3][256][512] f32 -> wk [72 chunks][512 n][32 kk] bf16 (chunk c: dydx=c/8, kc=c%8)
// kk pre-swizzled: kk ^ (((n>>1)&3)<<3) so the linear global_load_lds + swizzled ds_read match.
__global__ __launch_bounds__(256) void prep_wk(const float* __restrict__ w,
                                               unsigned short* __restrict__ wk) {
    __shared__ unsigned short t[32][130];
    const int c = blockIdx.x >> 2, nh = blockIdx.x & 3;
    const int dydx = c >> 3, kc = c & 7;
    #pragma unroll
    for (int e = 0; e < 16; ++e) {
        int idx = e * 256 + threadIdx.x;          // 32 kk x 128 n
        int kk = idx >> 7, n0 = idx & 127;
        float v = w[((size_t)(dydx * 256 + kc * 32 + kk)) * 512 + nh * 128 + n0];
        t[kk][n0] = f2bf(v);
    }
    __syncthreads();
    #pragma unroll
    for (int e = 0; e < 16; ++e) {
        int idx = e * 256 + threadIdx.x;          // 128 n x 32 kk
        int n0 = idx >> 5, kk = idx & 31;
        int n = nh * 128 + n0;
        int kks = kk ^ (((n >> 1) & 3) << 3);     // bank-conflict swizzle (64B rows)
        wk[(size_t)c * 16384 + (size_t)n * 32 + kks] = t[kk][n0];
    }
}

// w_cls [512][30], w_reg [512][60] -> wbr [96 n][512 k] bf16 (n 0..29=cls, 32..91=reg, rest 0)
__global__ __launch_bounds__(256) void prep_wbr(const float* __restrict__ wc,
                                                const float* __restrict__ wr,
                                                unsigned short* __restrict__ wbr) {
    int t = blockIdx.x * 256 + threadIdx.x;       // 49,152 total
    int n = t >> 9, k = t & 511;
    float v = 0.f;
    if (n < 30) v = wc[k * 30 + n];
    else if (n >= 32 && n < 92) v = wr[k * 60 + (n - 32)];
    wbr[n * 512 + k] = f2bf(v);
}

__global__ __launch_bounds__(512, 2) void rpn_fused(
    const float* __restrict__ x, const unsigned short* __restrict__ wk,
    const float* __restrict__ bsh, const unsigned short* __restrict__ wbr,
    const float* __restrict__ bcls, const float* __restrict__ breg,
    float* __restrict__ out)
{
    extern __shared__ char smem[];
    const int tid = threadIdx.x;
    const int lane = tid & 63;
    const int wid = tid >> 6;            // 0..7
    const int wm = wid >> 2, wn = wid & 3;
    const int l15 = lane & 15, l4 = lane >> 4;
    const int blk = blockIdx.x;
    const int bb = blk >> 7, h = blk & 127;

    // per-lane constant B offset parts: n0 = wn*128 + l15, swizzle S invariant across nf
    const int n0 = wn * 128 + l15;
    const int bofs = n0 * 64 + ((l4 * 16) ^ (((n0 >> 1) & 3) << 4));

    f32x4 acc[4][8];
    #pragma unroll
    for (int i = 0; i < 4; ++i)
        #pragma unroll
        for (int j = 0; j < 8; ++j) acc[i][j] = (f32x4){0.f, 0.f, 0.f, 0.f};

    // ---- prologue: stage chunk 0 into buf 0
    {
        const char* src = reinterpret_cast<const char*>(wk) + tid * 16;
        char* dst = smem + LDS_B_OFF + tid * 16;
        #pragma unroll
        for (int r = 0; r < 4; ++r)
            __builtin_amdgcn_global_load_lds(
                reinterpret_cast<const uint32_t*>(src + r * 8192),
                reinterpret_cast<uint32_t*>(dst + r * 8192), 16, 0, 0);
    }

    int g = 0;
    for (int dy = 0; dy < 3; ++dy) {
        // ---- A stage: rows protected by prev chunk's post-read barrier (or empty at dy=0)
        {
            const int hp = h + dy - 1;
            const bool hin = (hp >= 0) && (hp < HH);
            const float* xrow = x + ((size_t)(bb * HH + hp)) * WW * CIN;
            for (int u = tid; u < 130 * 32; u += 512) {
                const int pos = u >> 5, c8 = u & 31;
                const int wc = pos - 1;
                float4 f0 = make_float4(0.f,0.f,0.f,0.f), f1 = make_float4(0.f,0.f,0.f,0.f);
                if (hin && (unsigned)wc < WW) {
                    const float4* p = reinterpret_cast<const float4*>(xrow + (size_t)wc * CIN + c8 * 8);
                    f0 = p[0]; f1 = p[1];
                }
                short8 v;
                v[0]=(short)f2bf(f0.x); v[1]=(short)f2bf(f0.y);
                v[2]=(short)f2bf(f0.z); v[3]=(short)f2bf(f0.w);
                v[4]=(short)f2bf(f1.x); v[5]=(short)f2bf(f1.y);
                v[6]=(short)f2bf(f1.z); v[7]=(short)f2bf(f1.w);
                *reinterpret_cast<short8*>(smem + pos * 512 + ((c8 * 16) ^ ((pos & 7) << 4))) = v;
            }
        }
        for (int i = 0; i < 24; ++i, ++g) {
            const int nxt = g + 1;
            if (nxt < 72) {
                const char* src = reinterpret_cast<const char*>(wk) + (size_t)nxt * 32768 + tid * 16;
                char* dst = smem + LDS_B_OFF + ((nxt & 1) << 15) + tid * 16;
                #pragma unroll
                for (int r = 0; r < 4; ++r)
                    __builtin_amdgcn_global_load_lds(
                        reinterpret_cast<const uint32_t*>(src + r * 8192),
                        reinterpret_cast<uint32_t*>(dst + r * 8192), 16, 0, 0);
                if (i == 0) asm volatile("s_waitcnt vmcnt(4) lgkmcnt(0)" ::: "memory");
                else        asm volatile("s_waitcnt vmcnt(4)" ::: "memory");
            } else {
                asm volatile("s_waitcnt vmcnt(0) lgkmcnt(0)" ::: "memory");
            }
            __builtin_amdgcn_s_barrier();      // chunk g staged + A visible
            asm volatile("" ::: "memory");

            const int dx = (g >> 3) % 3;
            const int kc = g & 7;
            const char* bbuf = smem + LDS_B_OFF + ((g & 1) << 15);

            // A fragments (swizzle term identical for all mf: (r0+16k)&7 == r0&7)
            const int r0 = wm * 64 + l15 + dx;
            const int asw = ((kc * 32 + l4 * 8) * 2) ^ ((r0 & 7) << 4);
            short8 af0 = *reinterpret_cast<const short8*>(smem + (r0     ) * 512 + asw);
            short8 af1 = *reinterpret_cast<const short8*>(smem + (r0 + 16) * 512 + asw);
            short8 af2 = *reinterpret_cast<const short8*>(smem + (r0 + 32) * 512 + asw);
            short8 af3 = *reinterpret_cast<const short8*>(smem + (r0 + 48) * 512 + asw);

            // per-nf B read + 4 MFMAs: compiler emits counted lgkmcnt interleave
            __builtin_amdgcn_s_setprio(1);
            #pragma unroll
            for (int nf = 0; nf < 8; ++nf) {
                short8 bfv = *reinterpret_cast<const short8*>(bbuf + bofs + nf * 1024);
                acc[0][nf] = __builtin_amdgcn_mfma_f32_16x16x32_bf16(af0, bfv, acc[0][nf], 0, 0, 0);
                acc[1][nf] = __builtin_amdgcn_mfma_f32_16x16x32_bf16(af1, bfv, acc[1][nf], 0, 0, 0);
                acc[2][nf] = __builtin_amdgcn_mfma_f32_16x16x32_bf16(af2, bfv, acc[2][nf], 0, 0, 0);
                acc[3][nf] = __builtin_amdgcn_mfma_f32_16x16x32_bf16(af3, bfv, acc[3][nf], 0, 0, 0);
            }
            __builtin_amdgcn_s_setprio(0);
            __builtin_amdgcn_s_barrier();      // all waves done reading buf[g&1] / A row
            asm volatile("" ::: "memory");
        }
    }

    // ---- epilogue: bias + relu6 -> shared_act in LDS [128 pos][512 ch] bf16, swizzled
    __syncthreads();
    #pragma unroll
    for (int nf = 0; nf < 8; ++nf) {
        const int ch = wn * 128 + nf * 16 + l15;
        const float bv = bsh[ch];
        #pragma unroll
        for (int mf = 0; mf < 4; ++mf) {
            #pragma unroll
            for (int r = 0; r < 4; ++r) {
                const int pos = wm * 64 + mf * 16 + l4 * 4 + r;
                float v = acc[mf][nf][r] + bv;
                v = fminf(fmaxf(v, 0.f), 6.f);
                *reinterpret_cast<unsigned short*>(
                    smem + pos * 1024 + ((ch * 2) ^ ((pos & 7) << 4))) = f2bf(v);
            }
        }
    }
    __syncthreads();

    // ---- branch GEMM: per wave 16 pos x 96 out, K=512. A=shared_act(LDS), B=wbr(global, L2-hot)
    f32x4 bacc[6];
    #pragma unroll
    for (int nf = 0; nf < 6; ++nf) bacc[nf] = (f32x4){0.f,0.f,0.f,0.f};
    const int pos0 = wid * 16;
    #pragma unroll 4
    for (int kstep = 0; kstep < 16; ++kstep) {
        const int ch = kstep * 32 + l4 * 8;
        const int posr = pos0 + l15;
        short8 af = *reinterpret_cast<const short8*>(
            smem + posr * 1024 + ((ch * 2) ^ ((posr & 7) << 4)));
        #pragma unroll
        for (int nf = 0; nf < 6; ++nf) {
            const int n = nf * 16 + l15;
            short8 bfr = *reinterpret_cast<const short8*>(wbr + n * 512 + ch);
            bacc[nf] = __builtin_amdgcn_mfma_f32_16x16x32_bf16(af, bfr, bacc[nf], 0, 0, 0);
        }
    }

    // ---- branch epilogue: bias, pair-softmax (adjacent n -> shfl_xor 1), scattered f32 stores
    const size_t rowbase = (size_t)h * 128;
    #pragma unroll
    for (int nf = 0; nf < 2; ++nf) {                 // cls: n 0..31 (valid <30)
        const int n = nf * 16 + l15;
        const float bias = (n < 30) ? bcls[n] : 0.f;
        #pragma unroll
        for (int r = 0; r < 4; ++r) {
            float v = bacc[nf][r] + bias;
            float vo = __shfl_xor(v, 1);
            float mx = fmaxf(v, vo);
            float e  = __expf(v - mx), eo = __expf(vo - mx);
            float p  = e / (e + eo);
            if (n < 30) {
                const int wc = pos0 + l4 * 4 + r;
                const size_t anchor = (rowbase + wc) * 15 + (n >> 1);
                const size_t idx = (size_t)bb * 491520 + anchor * 2 + (n & 1);
                out[idx] = v;                        // rpn_class_logits
                out[3932160 + idx] = p;              // rpn_probs
            }
        }
    }
    #pragma unroll
    for (int nf = 2; nf < 6; ++nf) {                 // reg: n 32..95 (valid nr<60)
        const int n = nf * 16 + l15;
        const int nr = n - 32;
        const float bias = (nr < 60) ? breg[nr] : 0.f;
        #pragma unroll
        for (int r = 0; r < 4; ++r) {
            float v = bacc[nf][r] + bias;
            if (nr < 60) {
                const int wc = pos0 + l4 * 4 + r;
                const size_t anchor = (rowbase + wc) * 15 + (nr >> 2);
                out[7864320 + (size_t)bb * 983040 + anchor * 4 + (nr & 3)] = v;  // rpn_deltas
            }
        }
    }
}

extern "C" void kernel_launch(void* const* d_in, const int* in_sizes, int n_in,
                              void* d_out, int out_size, void* d_ws, size_t ws_size,
                              hipStream_t stream) {
    const float* x    = (const float*)d_in[0];
    const float* wsh  = (const float*)d_in[1];
    const float* bsh  = (const float*)d_in[2];
    const float* wcls = (const float*)d_in[3];
    const float* bcls = (const float*)d_in[4];
    const float* wreg = (const float*)d_in[5];
    const float* breg = (const float*)d_in[6];
    float* out = (float*)d_out;

    unsigned short* wk  = (unsigned short*)d_ws;          // 72*512*32 = 1,179,648 bf16 = 2.25 MiB
    unsigned short* wbr = wk + 1179648;                   // 49,152 bf16

    prep_wk <<<288, 256, 0, stream>>>(wsh, wk);
    prep_wbr<<<192, 256, 0, stream>>>(wcls, wreg, wbr);

    hipFuncSetAttribute((const void*)rpn_fused,
                        hipFuncAttributeMaxDynamicSharedMemorySize, LDS_TOTAL);
    rpn_fused<<<1024, 512, LDS_TOTAL, stream>>>(x, wk, bsh, wbr, bcls, breg, out);
}